// Round 2
// baseline (316.532 us; speedup 1.0000x reference)
//
#include <hip/hip_runtime.h>
#include <math.h>

// out = relu( tile(pool2(x1),2) + tile(pool4(x2),4) + tile(pool8(x3),8)
//             + tile(pool16(x4),16) + ff )   all NCHW fp32, B=16, out 16x256x24x24.
//
// Round-5: force deep memory-level parallelism.
// Round-4 evidence: VGPR_Count stayed 32 (compiler serialized the v[8] batches),
// occupancy 26->60% yet dur pinned ~117us, 2.1 TB/s, VALUBusy 3%.
// Little's law: 2.1 TB/s needs only ~3KB in flight per CU -> ~3 outstanding
// wave-loads per CU despite 19 resident waves. Latency-bound on request count.
//
// Fix: each thread issues ALL 31 float4 loads (ff + 2 A + 4 B + 8 C + 16 D)
// BEFORE consuming any, and consumes strictly in issue order (vmcnt retires
// in order -> counted waits, no forced drains). Pairwise-max trees keep every
// register live so the compiler cannot serialize: ~124 data VGPRs forced.
// __launch_bounds__(256,3): 168-VGPR budget, 3 blocks/CU (12 waves/CU);
// grid 2304 = 256 CU x 3 x 3 exact rounds, no tail imbalance.
// In-flight/CU: 12 waves x 64 lanes x up to 31 x 16B >> the ~9KB needed for
// peak HBM BW; expect BW-bound at >=4 TB/s.

namespace {

__device__ __forceinline__ float fmax4(const float4 v) {
  return fmaxf(fmaxf(v.x, v.y), fmaxf(v.z, v.w));
}

__device__ __forceinline__ float4 max4(const float4 a, const float4 b) {
  float4 r;
  r.x = fmaxf(a.x, b.x); r.y = fmaxf(a.y, b.y);
  r.z = fmaxf(a.z, b.z); r.w = fmaxf(a.w, b.w);
  return r;
}

__global__ __launch_bounds__(256, 3) void fused_block(const float* __restrict__ x1,
                                                      const float* __restrict__ x2,
                                                      const float* __restrict__ x3,
                                                      const float* __restrict__ x4,
                                                      const float* __restrict__ ff,
                                                      float* __restrict__ out) {
  // Transposed pooled tiles: s*t[col][ch], col = 0..3 of this block's 4 output cols.
  __shared__ float s1t[4 * 128];
  __shared__ float s2t[4 * 64];
  __shared__ float s3t[4 * 32];
  __shared__ float s4t[4 * 16];

  const int blk  = blockIdx.x;      // 0..2303
  const int b    = blk / 144;
  const int rem  = blk % 144;
  const int oh   = rem / 6;         // 0..23
  const int quad = rem % 6;         // output cols quad*4 .. quad*4+3
  const int tid  = threadIdx.x;

  // ================= ISSUE PHASE: 31 independent float4 loads =================

  // ff (consumed last, after the barrier)
  const size_t o = (size_t)b * 147456 + (size_t)tid * 576 + (size_t)oh * 24 + quad * 4;
  const float4 f = *reinterpret_cast<const float4*>(ff + o);

  // A: x1 [16,128,48,48], K=2. task = ch(128) x pid(2); 1 float4 = 2 windows.
  const int chA = tid >> 1, pidA = tid & 1;
  const float* pA = x1 + (size_t)b * 294912 + (size_t)chA * 2304
                       + oh * 96 + quad * 8 + pidA * 4;
  const float4 a0 = *reinterpret_cast<const float4*>(pA);
  const float4 a1 = *reinterpret_cast<const float4*>(pA + 48);

  // B: x2 [16,64,96,96], K=4. task = ch(64) x ow(4).
  const int chB = tid >> 2, owB = tid & 3;
  const float* pB = x2 + (size_t)b * 589824 + (size_t)chB * 9216
                       + oh * 384 + quad * 16 + owB * 4;
  float4 bv[4];
#pragma unroll
  for (int r = 0; r < 4; ++r) bv[r] = *reinterpret_cast<const float4*>(pB + r * 96);

  // C: x3 [16,32,192,192], K=8. task = ch(32) x ow(4) x hf(2); 2 lanes/window.
  const int chC = tid >> 3, owC = (tid >> 1) & 3, hf = tid & 1;
  const float* pC = x3 + (size_t)b * 1179648 + (size_t)chC * 36864
                       + oh * 1536 + quad * 32 + owC * 8 + hf * 4;
  float4 cv[8];
#pragma unroll
  for (int r = 0; r < 8; ++r) cv[r] = *reinterpret_cast<const float4*>(pC + r * 192);

  // D: x4 [16,16,384,384], K=16. task = ch(16) x ow(4) x q(4); 4 lanes/window.
  const int chD = tid >> 4, owD = (tid >> 2) & 3, q = tid & 3;
  const float* pD = x4 + (size_t)b * 2359296 + (size_t)chD * 147456
                       + oh * 6144 + quad * 64 + owD * 16 + q * 4;
  float4 dv[16];
#pragma unroll
  for (int r = 0; r < 16; ++r) dv[r] = *reinterpret_cast<const float4*>(pD + r * 384);

  // ============ CONSUME PHASE: strictly in issue order (counted vmcnt) ============

  // A
  s1t[(pidA * 2) * 128 + chA]     = fmaxf(fmaxf(a0.x, a0.y), fmaxf(a1.x, a1.y));
  s1t[(pidA * 2 + 1) * 128 + chA] = fmaxf(fmaxf(a0.z, a0.w), fmaxf(a1.z, a1.w));

  // B — pairwise tree keeps all 4 live.
  {
    const float4 u = max4(max4(bv[0], bv[1]), max4(bv[2], bv[3]));
    s2t[owB * 64 + chB] = fmax4(u);
  }

  // C — pairwise tree keeps all 8 live.
  {
    const float4 u0 = max4(cv[0], cv[1]), u1 = max4(cv[2], cv[3]);
    const float4 u2 = max4(cv[4], cv[5]), u3 = max4(cv[6], cv[7]);
    float m = fmax4(max4(max4(u0, u1), max4(u2, u3)));
    m = fmaxf(m, __shfl_xor(m, 1));
    if (hf == 0) s3t[owC * 32 + chC] = m;
  }

  // D — pairwise tree keeps all 16 live.
  {
    float4 t[8];
#pragma unroll
    for (int r = 0; r < 8; ++r) t[r] = max4(dv[r], dv[r + 8]);
    const float4 u0 = max4(t[0], t[1]), u1 = max4(t[2], t[3]);
    const float4 u2 = max4(t[4], t[5]), u3 = max4(t[6], t[7]);
    float m = fmax4(max4(max4(u0, u1), max4(u2, u3)));
    m = fmaxf(m, __shfl_xor(m, 1));
    m = fmaxf(m, __shfl_xor(m, 2));
    if (q == 0) s4t[owD * 16 + chD] = m;
  }

  __syncthreads();

  // E: combine. task = channel(256); float4 over this block's 4 cols.
  {
    const int c1 = tid & 127, c2 = tid & 63, c3 = tid & 31, c4 = tid & 15;
    float4 r;
    r.x = fmaxf(s1t[0 * 128 + c1] + s2t[0 * 64 + c2] + s3t[0 * 32 + c3] + s4t[0 * 16 + c4] + f.x, 0.0f);
    r.y = fmaxf(s1t[1 * 128 + c1] + s2t[1 * 64 + c2] + s3t[1 * 32 + c3] + s4t[1 * 16 + c4] + f.y, 0.0f);
    r.z = fmaxf(s1t[2 * 128 + c1] + s2t[2 * 64 + c2] + s3t[2 * 32 + c3] + s4t[2 * 16 + c4] + f.z, 0.0f);
    r.w = fmaxf(s1t[3 * 128 + c1] + s2t[3 * 64 + c2] + s3t[3 * 32 + c3] + s4t[3 * 16 + c4] + f.w, 0.0f);
    *reinterpret_cast<float4*>(out + o) = r;
  }
}

}  // namespace

extern "C" void kernel_launch(void* const* d_in, const int* in_sizes, int n_in,
                              void* d_out, int out_size, void* d_ws, size_t ws_size,
                              hipStream_t stream) {
  const float* x1 = (const float*)d_in[0];  // [16,128,48,48]
  const float* x2 = (const float*)d_in[1];  // [16,64,96,96]
  const float* x3 = (const float*)d_in[2];  // [16,32,192,192]
  const float* x4 = (const float*)d_in[3];  // [16,16,384,384]
  const float* ff = (const float*)d_in[4];  // [16,256,24,24]
  float* out = (float*)d_out;               // [16,256,24,24]
  (void)d_ws; (void)ws_size; (void)in_sizes; (void)n_in; (void)out_size;

  fused_block<<<2304, 256, 0, stream>>>(x1, x2, x3, x4, ff, out);
}